// Round 1
// baseline (1315.562 us; speedup 1.0000x reference)
//
#include <hip/hip_runtime.h>
#include <math.h>

// Problem constants (from reference)
constexpr int kB    = 1024;     // batch
constexpr int kP    = 10;       // positives per row
constexpr int kNeg  = 990;      // negatives per row
constexpr int kCols = 1000;     // P + NEG
constexpr int kNI1  = 20001;    // NI + 1 (stats row stride)
constexpr long long kStatsN = 200030001LL; // (NU+1)*(NI+1)
constexpr float kMom = 0.9f;
constexpr float kEps = 1e-10f;

// Workspace layout (floats unless noted)
// [0..1023]      T0[b]   = sum_j exp(neg)
// [1024..2047]   T1[b]   = sum_j neg*exp(neg)
// [2048..3071]   mm[b]   = maxneg - minpos
// [3072..4095]   fair[b] = (diff*sqrt(FW))^2
// [4096] M   [4097] fair_sum   [4098] main_acc
// [4100..14339]  upd[k]  (k = b*P+p, 10240)
// [14340..24579] key[k]  (int)
constexpr int kOffT0   = 0;
constexpr int kOffT1   = 1024;
constexpr int kOffMM   = 2048;
constexpr int kOffFair = 3072;
constexpr int kOffM    = 4096;
constexpr int kOffFS   = 4097;
constexpr int kOffAcc  = 4098;
constexpr int kOffUpd  = 4100;
constexpr int kOffKey  = 14340;

__device__ inline float wave_sum(float v) {
    for (int o = 32; o > 0; o >>= 1) v += __shfl_xor(v, o, 64);
    return v;
}
__device__ inline float wave_max(float v) {
    for (int o = 32; o > 0; o >>= 1) v = fmaxf(v, __shfl_xor(v, o, 64));
    return v;
}
__device__ inline float wave_min(float v) {
    for (int o = 32; o > 0; o >>= 1) v = fminf(v, __shfl_xor(v, o, 64));
    return v;
}

// K1: per-batch-row reductions (1024 blocks x 256 threads)
__global__ __launch_bounds__(256) void k_rowstats(const float* __restrict__ pred,
                                                  const float* __restrict__ aidx,
                                                  const float* __restrict__ bidx,
                                                  float* __restrict__ ws) {
    const int b = blockIdx.x;
    const int t = threadIdx.x;
    const float* row = pred + (long long)b * kCols;
    const float* ar  = aidx + (long long)b * kCols;
    const float* br  = bidx + (long long)b * kCols;

    float sumexp = 0.f, sa = 0.f, sb = 0.f, T0 = 0.f, T1 = 0.f;
    float posmin = INFINITY, negmax = -INFINITY;
#pragma unroll
    for (int q = 0; q < 4; ++q) {
        int i = t + q * 256;
        if (i < kCols) {
            float x  = row[i];
            float ex = expf(x);
            sumexp += ex;
            sa += ar[i] * ex;
            sb += br[i] * ex;
            if (i < kP) {
                posmin = fminf(posmin, x);
            } else {
                negmax = fmaxf(negmax, x);
                T0 += ex;
                T1 += x * ex;
            }
        }
    }
    // wave-level reduce
    sumexp = wave_sum(sumexp);
    sa     = wave_sum(sa);
    sb     = wave_sum(sb);
    T0     = wave_sum(T0);
    T1     = wave_sum(T1);
    posmin = wave_min(posmin);
    negmax = wave_max(negmax);

    __shared__ float red[7][4];
    const int w = t >> 6, lane = t & 63;
    if (lane == 0) {
        red[0][w] = sumexp; red[1][w] = sa; red[2][w] = sb;
        red[3][w] = T0;     red[4][w] = T1;
        red[5][w] = posmin; red[6][w] = negmax;
    }
    __syncthreads();
    if (t == 0) {
        float se = 0.f, a = 0.f, bb = 0.f, t0 = 0.f, t1 = 0.f;
        float pm = INFINITY, nm = -INFINITY;
#pragma unroll
        for (int i = 0; i < 4; ++i) {
            se += red[0][i]; a += red[1][i]; bb += red[2][i];
            t0 += red[3][i]; t1 += red[4][i];
            pm = fminf(pm, red[5][i]); nm = fmaxf(nm, red[6][i]);
        }
        float diff = (bb - a) / se;
        float fw   = sqrtf(100000.0f);
        float d2   = diff * fw;
        ws[kOffT0 + b]   = t0;
        ws[kOffT1 + b]   = t1;
        ws[kOffMM + b]   = nm - pm;
        ws[kOffFair + b] = d2 * d2;
    }
}

// K2: reduce 1024 row values -> global M, fairness sum; zero the main accumulator
__global__ __launch_bounds__(256) void k_reduce(float* __restrict__ ws) {
    const int t = threadIdx.x;
    float mm = -INFINITY, fs = 0.f;
#pragma unroll
    for (int q = 0; q < 4; ++q) {
        int i = t + q * 256;
        mm = fmaxf(mm, ws[kOffMM + i]);
        fs += ws[kOffFair + i];
    }
    mm = wave_max(mm);
    fs = wave_sum(fs);
    __shared__ float rm[4], rs[4];
    const int w = t >> 6, lane = t & 63;
    if (lane == 0) { rm[w] = mm; rs[w] = fs; }
    __syncthreads();
    if (t == 0) {
        float M = fmaxf(fmaxf(rm[0], rm[1]), fmaxf(rm[2], rm[3]));
        float F = rs[0] + rs[1] + rs[2] + rs[3];
        ws[kOffM]   = M;
        ws[kOffFS]  = F;
        ws[kOffAcc] = 0.f;
    }
}

// K3: per-(b,p) updated stats + main-loss partial sums (40 blocks x 256)
__global__ __launch_bounds__(256) void k_perk(const float* __restrict__ pred,
                                              const float* __restrict__ stats,
                                              const int* __restrict__ uid,
                                              const int* __restrict__ iid,
                                              float* __restrict__ ws) {
    const int k = blockIdx.x * 256 + threadIdx.x;   // exactly 10240 threads
    const float M = ws[kOffM];
    const int b = k / kP;
    const int p = k - b * kP;
    float pos = pred[(long long)b * kCols + p];
    float T0  = ws[kOffT0 + b];
    float T1  = ws[kOffT1 + b];
    float s   = expf(-pos - M);
    float mean_e = s * T0 * (1.0f / kNeg);
    int u  = uid[b];
    int it = iid[k];
    int key = u * kNI1 + it;
    float cur = stats[(long long)key];
    float upd = (1.0f - kMom) * cur + kMom * mean_e;
    ws[kOffUpd + k] = upd;
    ((int*)ws)[kOffKey + k] = key;
    float c = s * (T1 - pos * T0) / (upd + kEps);

    c = wave_sum(c);
    __shared__ float rs[4];
    const int w = threadIdx.x >> 6, lane = threadIdx.x & 63;
    if (lane == 0) rs[w] = c;
    __syncthreads();
    if (threadIdx.x == 0) {
        atomicAdd(&ws[kOffAcc], rs[0] + rs[1] + rs[2] + rs[3]);
    }
}

// K4: big copy stats -> out+1 (fully coalesced, 4 elems/thread)
__global__ __launch_bounds__(256) void k_copy(const float* __restrict__ src,
                                              float* __restrict__ dst) {
    const long long base = (long long)blockIdx.x * 1024 + threadIdx.x;
#pragma unroll
    for (int q = 0; q < 4; ++q) {
        long long i = base + (long long)q * 256;
        if (i < kStatsN) dst[i] = src[i];
    }
}

// K5: scatter updated values (last-occurrence-wins like numpy) + write loss
__global__ __launch_bounds__(256) void k_scatter(float* __restrict__ out,
                                                 const float* __restrict__ ws) {
    const int k = blockIdx.x;
    const int* keys = (const int*)ws + kOffKey;
    __shared__ int dupflag;
    if (threadIdx.x == 0) dupflag = 0;
    __syncthreads();
    const int key = keys[k];
    for (int j = k + 1 + threadIdx.x; j < kB * kP; j += 256) {
        if (keys[j] == key) dupflag = 1;   // benign race, same value
    }
    __syncthreads();
    if (threadIdx.x == 0 && !dupflag) {
        out[1 + (long long)key] = ws[kOffUpd + k];
    }
    if (blockIdx.x == 0 && threadIdx.x == 255) {
        out[0] = ws[kOffAcc] * (1.0f / kB) + ws[kOffFS] * (1.0f / kB);
    }
}

extern "C" void kernel_launch(void* const* d_in, const int* in_sizes, int n_in,
                              void* d_out, int out_size, void* d_ws, size_t ws_size,
                              hipStream_t stream) {
    const float* pred  = (const float*)d_in[0];
    const float* stats = (const float*)d_in[1];
    const int*   uid   = (const int*)d_in[2];
    const int*   iid   = (const int*)d_in[3];
    const float* aidx  = (const float*)d_in[4];
    const float* bidx  = (const float*)d_in[5];
    float* out = (float*)d_out;
    float* ws  = (float*)d_ws;

    k_rowstats<<<kB, 256, 0, stream>>>(pred, aidx, bidx, ws);
    k_reduce<<<1, 256, 0, stream>>>(ws);
    k_perk<<<(kB * kP) / 256, 256, 0, stream>>>(pred, stats, uid, iid, ws);
    long long nblocks = (kStatsN + 1023) / 1024;
    k_copy<<<(int)nblocks, 256, 0, stream>>>(stats, out + 1);
    k_scatter<<<kB * kP, 256, 0, stream>>>(out, ws);
}